// Round 18
// baseline (997.306 us; speedup 1.0000x reference)
//
#include <hip/hip_runtime.h>
#include <cstdint>
#include <cstddef>

// Nystromformer attention block for MI355X (gfx950).
// B=4, S=4096, DIM=1024, H=16, D=64, m=256 landmarks.

typedef unsigned short u16;
typedef __attribute__((ext_vector_type(8))) short short8;
typedef __attribute__((ext_vector_type(4))) float f32x4;
typedef __attribute__((ext_vector_type(4))) unsigned short us4;
typedef __attribute__((ext_vector_type(8))) unsigned short us8;

__device__ __forceinline__ float bf2f(u16 u){ return __uint_as_float(((unsigned int)u)<<16); }
__device__ __forceinline__ u16 f2bf(float x){
  unsigned int i = __float_as_uint(x);
  unsigned int r = i + 0x7FFFu + ((i>>16)&1u);   // RNE
  return (u16)(r>>16);
}
__device__ __forceinline__ f32x4 mfma16(short8 a, short8 b, f32x4 c){
  return __builtin_amdgcn_mfma_f32_16x16x32_bf16(a,b,c,0,0,0);
}
__device__ __forceinline__ void gld16(const void* g, void* l){
  __builtin_amdgcn_global_load_lds(
      (const __attribute__((address_space(1))) unsigned int*)g,
      (__attribute__((address_space(3))) unsigned int*)l, 16, 0, 0);
}
// native exp (v_exp_f32): ~3 VALU inst vs ~15 for libm expf; ~2ulp accuracy
__device__ __forceinline__ float fexp(float x){ return __expf(x); }

// ---------- k2 = softmax(Ql @ Kl^T) from pre-split hi/lo operands ----------
__global__ __launch_bounds__(256) void k2s_k(
    const u16* __restrict__ Ah, const u16* __restrict__ Al,
    const u16* __restrict__ Bh, const u16* __restrict__ Bl,
    float* __restrict__ C)
{
  __shared__ u16 lds[40960];   // Ah@0(4096) Al@4096 Bh@8192(16384) Bl@24576
  const int tid = threadIdx.x;
  const int tileM = blockIdx.x*64;
  const int z = blockIdx.y;
  const int lane = tid&63, wv = tid>>6;
  const int lrow = lane&15, kgrp = lane>>4;
  const u16* baseAh = Ah + (size_t)z*16384 + (size_t)tileM*64;
  const u16* baseAl = Al + (size_t)z*16384 + (size_t)tileM*64;
  const u16* baseBh = Bh + (size_t)z*16384;
  const u16* baseBl = Bl + (size_t)z*16384;

  #pragma unroll
  for (int it=0; it<2; ++it){
    int w = it*256 + tid; int row = w>>3, c = w&7; int cs = c^(row&7);
    gld16(baseAh + (size_t)row*64 + (cs<<3), lds + (w & ~63)*8);
  }
  #pragma unroll
  for (int it=0; it<2; ++it){
    int w = it*256 + tid; int row = w>>3, c = w&7; int cs = c^(row&7);
    gld16(baseAl + (size_t)row*64 + (cs<<3), lds + 4096 + (w & ~63)*8);
  }
  #pragma unroll
  for (int it=0; it<8; ++it){
    int w = it*256 + tid; int row = w>>3, c = w&7; int cs = c^(row&7);
    gld16(baseBh + (size_t)row*64 + (cs<<3), lds + 8192 + (w & ~63)*8);
  }
  #pragma unroll
  for (int it=0; it<8; ++it){
    int w = it*256 + tid; int row = w>>3, c = w&7; int cs = c^(row&7);
    gld16(baseBl + (size_t)row*64 + (cs<<3), lds + 24576 + (w & ~63)*8);
  }
  __syncthreads();

  f32x4 acc[16];
  #pragma unroll
  for (int j=0;j<16;j++) acc[j] = (f32x4){0.f,0.f,0.f,0.f};

  #pragma unroll
  for (int kt=0; kt<2; ++kt){
    int ch = kt*4 + kgrp;
    int ra = wv*16 + lrow;
    short8 ah = *(const short8*)&lds[ra*64 + ((ch^(ra&7))<<3)];
    short8 al = *(const short8*)&lds[4096 + ra*64 + ((ch^(ra&7))<<3)];
    #pragma unroll
    for (int j=0;j<16;j++){
      int rb = j*16 + lrow;
      short8 bh = *(const short8*)&lds[8192 + rb*64 + ((ch^(rb&7))<<3)];
      short8 bl = *(const short8*)&lds[24576 + rb*64 + ((ch^(rb&7))<<3)];
      acc[j] = mfma16(ah, bh, acc[j]);
      acc[j] = mfma16(ah, bl, acc[j]);
      acc[j] = mfma16(al, bh, acc[j]);
    }
  }

  float* Cz = C + (size_t)z*65536;
  #pragma unroll
  for (int r=0;r<4;r++){
    float mx = -3.0e38f;
    #pragma unroll
    for (int j=0;j<16;j++) mx = fmaxf(mx, acc[j][r]);
    #pragma unroll
    for (int d=1; d<16; d<<=1) mx = fmaxf(mx, __shfl_xor(mx, d));
    float p[16]; float ss = 0.f;
    #pragma unroll
    for (int j=0;j<16;j++){ p[j] = fexp(acc[j][r]-mx); ss += p[j]; }
    #pragma unroll
    for (int d=1; d<16; d<<=1) ss += __shfl_xor(ss, d);
    float inv = 1.0f/ss;
    int row = tileM + wv*16 + kgrp*4 + r;
    #pragma unroll
    for (int j=0;j<16;j++){
      int col = j*16 + lrow;
      Cz[(size_t)row*256 + col] = p[j]*inv;
    }
  }
}

// ---------- pre-split bf16 GEMM: C = A[M,K] * B^T with A,B as hi/lo pairs ----------
// OUT 0: Newton epilogue. OUT 1: tT bf16 transpose out. OUT 2: f32 landmark scatter.
template<int OUT>
__global__ __launch_bounds__(256) void sgemm_k(
    const u16* __restrict__ Ah, const u16* __restrict__ Al,
    const u16* __restrict__ Bh, const u16* __restrict__ Bl,
    int K, long long sA, long long sB,
    u16* __restrict__ RoH, u16* __restrict__ RoL,
    u16* __restrict__ CoH, u16* __restrict__ CoL,
    float* __restrict__ Fo, long long sO, int ldO,
    float addI, float csgn, float scale,
    const float* __restrict__ bias, const float* __restrict__ ml)
{
  __shared__ u16 lds[16384];
  const int tid = threadIdx.x;
  const int z = blockIdx.z;
  const int tileM = blockIdx.x*64, tileN = blockIdx.y*64;
  const int lane = tid&63, wv = tid>>6;
  const int wr = wv>>1, wc = wv&1;
  const int lrow = lane&15, kgrp = lane>>4;

  const u16* __restrict__ base[4] = {
    Ah + (size_t)z*sA + (size_t)tileM*K,
    Al + (size_t)z*sA + (size_t)tileM*K,
    Bh + (size_t)z*sB + (size_t)tileN*K,
    Bl + (size_t)z*sB + (size_t)tileN*K };

  f32x4 acc[2][2];
  #pragma unroll
  for (int i=0;i<2;i++)
    #pragma unroll
    for (int j=0;j<2;j++) acc[i][j] = (f32x4){0.f,0.f,0.f,0.f};

  for (int k0=0; k0<K; k0+=64){
    #pragma unroll
    for (int t4=0; t4<4; ++t4){
      #pragma unroll
      for (int hf=0; hf<2; ++hf){
        int w = hf*256 + tid;
        int row = w>>3, c = w&7;
        int cs = c ^ (row&7);
        gld16(base[t4] + (size_t)row*K + k0 + cs*8, lds + t4*4096 + (w & ~63)*8);
      }
    }
    __syncthreads();
    #pragma unroll
    for (int kk=0; kk<2; ++kk){
      int ch = kk*4 + kgrp;
      short8 a_h[2], a_l[2], b_h[2], b_l[2];
      #pragma unroll
      for (int i=0;i<2;i++){
        int r = wr*32 + i*16 + lrow;
        int off = r*64 + ((ch ^ (r&7))<<3);
        a_h[i] = *(const short8*)&lds[off];
        a_l[i] = *(const short8*)&lds[4096 + off];
      }
      #pragma unroll
      for (int j=0;j<2;j++){
        int r = wc*32 + j*16 + lrow;
        int off = r*64 + ((ch ^ (r&7))<<3);
        b_h[j] = *(const short8*)&lds[8192 + off];
        b_l[j] = *(const short8*)&lds[12288 + off];
      }
      #pragma unroll
      for (int i=0;i<2;i++)
        #pragma unroll
        for (int j=0;j<2;j++){
          acc[i][j] = mfma16(a_h[i], b_h[j], acc[i][j]);
          acc[i][j] = mfma16(a_h[i], b_l[j], acc[i][j]);
          acc[i][j] = mfma16(a_l[i], b_h[j], acc[i][j]);
        }
    }
    __syncthreads();
  }

  if constexpr (OUT==0 || OUT==1){
    #pragma unroll
    for (int i=0;i<2;i++)
      #pragma unroll
      for (int j=0;j<2;j++){
        int rl0 = wr*32 + i*16 + kgrp*4;
        int cl  = wc*32 + j*16 + lrow;
        #pragma unroll
        for (int q=0;q<4;q++){
          int rl = rl0 + q;
          float p = acc[i][j][q]*scale;
          if constexpr (OUT==0){
            if (RoH){
              u16 h = f2bf(p);
              int lo = rl*64 + (cl ^ ((rl&7)<<3));
              lds[lo] = h;
              lds[4096 + lo] = f2bf(p - bf2f(h));
            }
            float cv = csgn*p + (((tileM+rl)==(tileN+cl))? addI : 0.f);
            u16 ch = f2bf(cv);
            int lo2 = cl*64 + (rl ^ ((cl&7)<<3));
            lds[8192 + lo2] = ch;
            lds[12288 + lo2] = f2bf(cv - bf2f(ch));
          } else {
            lds[cl*64 + (rl ^ ((cl&7)<<3))] = f2bf(p);
          }
        }
      }
    __syncthreads();
    if constexpr (OUT==0){
      if (RoH){
        #pragma unroll
        for (int c2=0;c2<2;c2++){
          int idx = c2*256 + tid;
          int row = idx>>3, seg = idx&7;
          int lo = row*64 + ((seg ^ (row&7))<<3);
          size_t go = (size_t)z*65536 + (size_t)(tileM+row)*256 + tileN + seg*8;
          *(us8*)&RoH[go] = *(const us8*)&lds[lo];
          *(us8*)&RoL[go] = *(const us8*)&lds[4096 + lo];
        }
      }
      #pragma unroll
      for (int c2=0;c2<2;c2++){
        int idx = c2*256 + tid;
        int row = idx>>3, seg = idx&7;
        int lo = row*64 + ((seg ^ (row&7))<<3);
        size_t go = (size_t)z*65536 + (size_t)(tileN+row)*256 + tileM + seg*8;
        *(us8*)&CoH[go] = *(const us8*)&lds[8192 + lo];
        *(us8*)&CoL[go] = *(const us8*)&lds[12288 + lo];
      }
    } else {
      #pragma unroll
      for (int c2=0;c2<2;c2++){
        int idx = c2*256 + tid;
        int row = idx>>3, seg = idx&7;
        int lo = row*64 + ((seg ^ (row&7))<<3);
        *(us8*)&CoH[(size_t)z*16384 + (size_t)(tileN+row)*256 + tileM + seg*8] =
            *(const us8*)&lds[lo];
      }
    }
  } else {
    #pragma unroll
    for (int i=0;i<2;i++)
      #pragma unroll
      for (int j=0;j<2;j++){
        int grow0 = tileM + wr*32 + i*16 + kgrp*4;
        int gcol  = tileN + wc*32 + j*16 + lrow;
        #pragma unroll
        for (int q=0;q<4;q++){
          int grow = grow0+q;
          float v = acc[i][j][q] + ml[grow]*bias[gcol];
          int b = grow>>8, l = grow&255, h = gcol>>6, d = gcol&63;
          size_t oi = (((size_t)(b*16+h)*256 + l)*64 + d);
          Fo[oi] = v;
          if (RoH){
            u16 hh = f2bf(v);
            RoH[oi] = hh;
            RoL[oi] = f2bf(v - bf2f(hh));
          }
        }
      }
  }
}

// ---------- fast bf16 GEMM: 256x128 tile, 8 waves (512 thr), wave tile 64x64 ----------
// Accumulation chain per output element identical to prior versions (bit-identical).
// EPI 0: f32 row-major out. EPI 1: QKV scatter via LDS-bounce in two 128-row passes.
template<int EPI>
__global__ __launch_bounds__(512) void fgemm_k(
    const u16* __restrict__ A, const u16* __restrict__ Bt, float* __restrict__ Cf,
    u16* __restrict__ Q_, u16* __restrict__ K_, u16* __restrict__ V_,
    int M, int N, int K, int nTilesN,
    const float* __restrict__ bias, const float* __restrict__ rowscale)
{
  __shared__ u16 lds[24576];   // A [256][64] @0 (16384 u16), B [128][64] @16384 (8192 u16)
  u16* ldsA = lds;
  u16* ldsB = lds + 16384;

  int flat = blockIdx.y*nTilesN + blockIdx.x;
  int nwg  = gridDim.x*gridDim.y;
  int chunk = nwg >> 3;
  int nid = (flat & 7)*chunk + (flat >> 3);
  int bxM = nid / nTilesN, byN = nid % nTilesN;
  const int tileM = bxM*256, tileN = byN*128;

  const int tid = threadIdx.x;
  const int lane = tid & 63, wv = tid>>6;
  const int wr = wv>>1, wc = wv&1;          // 4 x 2 wave grid, wave tile 64x64
  const int lrow = lane&15, kgrp = lane>>4;

  f32x4 acc[4][4];
  #pragma unroll
  for (int i=0;i<4;i++)
    #pragma unroll
    for (int j=0;j<4;j++) acc[i][j] = (f32x4){0.f,0.f,0.f,0.f};

  for (int k0=0; k0<K; k0+=64){
    #pragma unroll
    for (int i=0;i<4;i++){
      int s = i*512 + tid;
      int row = s>>3, c = s&7;
      int cs = c ^ (row&7);
      gld16(A + (size_t)(tileM+row)*K + k0 + cs*8, ldsA + (size_t)(s & ~63)*8);
    }
    #pragma unroll
    for (int i=0;i<2;i++){
      int s = i*512 + tid;
      int row = s>>3, c = s&7;
      int cs = c ^ (row&7);
      gld16(Bt + (size_t)(tileN+row)*K + k0 + cs*8, ldsB + (size_t)(s & ~63)*8);
    }
    __syncthreads();
    #pragma unroll
    for (int kk=0; kk<2; ++kk){
      int ch = kk*4 + kgrp;
      short8 af[4], bf[4];
      #pragma unroll
      for (int i=0;i<4;i++){
        int r = wr*64 + i*16 + lrow;
        af[i] = *(const short8*)&ldsA[r*64 + ((ch^(r&7))<<3)];
      }
      #pragma unroll
      for (int j=0;j<4;j++){
        int r = wc*64 + j*16 + lrow;
        bf[j] = *(const short8*)&ldsB[r*64 + ((ch^(r&7))<<3)];
      }
      #pragma unroll
      for (int i=0;i<4;i++)
        #pragma unroll
        for (int j=0;j<4;j++)
          acc[i][j] = mfma16(af[i], bf[j], acc[i][j]);
    }
    __syncthreads();
  }

  if constexpr (EPI==0){
    #pragma unroll
    for (int i=0;i<4;i++)
      #pragma unroll
      for (int j=0;j<4;j++)
        #pragma unroll
        for (int q=0;q<4;q++){
          int row = tileM + wr*64 + i*16 + kgrp*4 + q;
          int col = tileN + wc*64 + j*16 + lrow;
          Cf[(size_t)row*N + col] = acc[i][j][q] + (bias ? bias[col] : 0.f);
        }
  } else {
    // LDS-bounce in two 128-row passes (each [128][128] bf16 = 32 KB)
    #pragma unroll
    for (int p=0; p<2; ++p){
      if ((wr>>1) == p){
        #pragma unroll
        for (int i=0;i<4;i++)
          #pragma unroll
          for (int j=0;j<4;j++)
            #pragma unroll
            for (int q=0;q<4;q++){
              int rloc = (wr&1)*64 + i*16 + kgrp*4 + q;   // 0..127 within pass
              int cloc = wc*64 + j*16 + lrow;
              int col = tileN + cloc;
              float v = acc[i][j][q] + bias[col];
              if ((col>>10) < 2) v *= rowscale[tileM + p*128 + rloc];
              lds[rloc*128 + cloc] = f2bf(v);
            }
      }
      __syncthreads();
      #pragma unroll
      for (int c=0;c<4;c++){
        int idx = c*512 + tid;
        int row = idx >> 4;       // 0..127
        int seg = idx & 15;       // 8 elems each
        int col = tileN + seg*8;
        int which = col >> 10;
        int hd = col & 1023, h = hd>>6, d0 = hd&63;
        int grow = tileM + p*128 + row;
        int b = grow>>12, s = grow&4095;
        u16* dst = (which==0) ? Q_ : (which==1) ? K_ : V_;
        us8 v = *(const us8*)&lds[row*128 + seg*8];
        *(us8*)&dst[(((size_t)(b*16+h))*4096 + s)*64 + d0] = v;
      }
      __syncthreads();
    }
  }
}

// ---------- flash O3 partials: chunked softmax(Ql @ K^T + maskbias) @ V ----------
__global__ __launch_bounds__(256) void o3p_k(
    const float* __restrict__ Ql, const u16* __restrict__ Kb, const u16* __restrict__ Vb,
    const float* __restrict__ mask, float* __restrict__ Opart, float* __restrict__ MLpart)
{
  constexpr int QHI=0, QLO=4096, KT=8192, VT=12288, PHI=16640, PLO=20736;
  __shared__ u16 lds[24832];
  const int bx = blockIdx.x, ck = blockIdx.y, z = blockIdx.z;
  const int tid = threadIdx.x;
  const int lane = tid&63, wv = tid>>6;
  const int lrow = lane&15, kgrp = lane>>4;
  const float* Qlz = Ql + (size_t)z*16384 + (size_t)bx*64*64;
  const u16* Kz = Kb + (size_t)z*4096*64;
  const u16* Vz = Vb + (size_t)z*4096*64;
  const float* mrow = mask + (size_t)(z>>4)*4096;

  #pragma unroll
  for (int i=0;i<2;i++){
    int s = i*256 + tid;
    int row = s>>3, c = s&7;
    const float* src = Qlz + row*64 + c*8;
    f32x4 v0 = *(const f32x4*)src;
    f32x4 v1 = *(const f32x4*)(src+4);
    us8 hi, lo;
    #pragma unroll
    for (int e=0;e<4;e++){
      hi[e] = f2bf(v0[e]); lo[e] = f2bf(v0[e]-bf2f(hi[e]));
      hi[4+e] = f2bf(v1[e]); lo[4+e] = f2bf(v1[e]-bf2f(hi[4+e]));
    }
    int ad = row*64 + ((c^(row&7))<<3);
    *(us8*)&lds[QHI+ad] = hi;
    *(us8*)&lds[QLO+ad] = lo;
  }

  float m_r[4], l_r[4];
  f32x4 oacc[4];
  #pragma unroll
  for (int r=0;r<4;r++){ m_r[r] = -3.0e38f; l_r[r] = 0.f; }
  #pragma unroll
  for (int j=0;j<4;j++) oacc[j] = (f32x4){0.f,0.f,0.f,0.f};

  for (int st=0; st<16; ++st){
    int s0 = (ck*16 + st)*64;
    #pragma unroll
    for (int i=0;i<2;i++){
      int s = i*256 + tid;
      int row = s>>3, c = s&7;
      int cs = c ^ (row&7);
      gld16(Kz + (size_t)(s0+row)*64 + cs*8, &lds[KT + (size_t)(s & ~63)*8]);
    }
    #pragma unroll
    for (int i=0;i<2;i++){
      int s = i*256 + tid;
      int row = s>>3, c = s&7;
      us8 v = *(const us8*)(Vz + (size_t)(s0+row)*64 + c*8);
      #pragma unroll
      for (int e=0;e<8;e++) lds[VT + (c*8+e)*68 + row] = v[e];
    }
    __syncthreads();

    f32x4 sacc[4];
    #pragma unroll
    for (int j=0;j<4;j++) sacc[j] = (f32x4){0.f,0.f,0.f,0.f};
    int qr = wv*16 + lrow;
    #pragma unroll
    for (int kk=0; kk<2; ++kk){
      int ch = kk*4 + kgrp;
      short8 ah = *(const short8*)&lds[QHI + qr*64 + ((ch^(qr&7))<<3)];
      short8 alo = *(const short8*)&lds[QLO + qr*64 + ((ch^(qr&7))<<3)];
      #pragma unroll
      for (int j=0;j<4;j++){
        int kr = j*16 + lrow;
        short8 bk = *(const short8*)&lds[KT + kr*64 + ((ch^(kr&7))<<3)];
        sacc[j] = mfma16(ah, bk, sacc[j]);
        sacc[j] = mfma16(alo, bk, sacc[j]);
      }
    }
    float mb[4];
    #pragma unroll
    for (int j=0;j<4;j++) mb[j] = -1.0e9f*(1.0f - mrow[s0 + j*16 + lrow]);
    #pragma unroll
    for (int j=0;j<4;j++)
      #pragma unroll
      for (int r=0;r<4;r++) sacc[j][r] += mb[j];

    #pragma unroll
    for (int r=0;r<4;r++){
      float tm = fmaxf(fmaxf(sacc[0][r],sacc[1][r]), fmaxf(sacc[2][r],sacc[3][r]));
      #pragma unroll
      for (int d=1; d<16; d<<=1) tm = fmaxf(tm, __shfl_xor(tm, d));
      float mn = fmaxf(m_r[r], tm);
      float scf = fexp(m_r[r] - mn);
      float ps[4]; float tsum = 0.f;
      #pragma unroll
      for (int j=0;j<4;j++){ ps[j] = fexp(sacc[j][r] - mn); tsum += ps[j]; }
      #pragma unroll
      for (int d=1; d<16; d<<=1) tsum += __shfl_xor(tsum, d);
      l_r[r] = l_r[r]*scf + tsum;
      m_r[r] = mn;
      #pragma unroll
      for (int j=0;j<4;j++) oacc[j][r] *= scf;
      int prow = kgrp*4 + r;
      #pragma unroll
      for (int j=0;j<4;j++){
        int key = j*16 + lrow;
        u16 phi = f2bf(ps[j]);
        u16 plo = f2bf(ps[j] - bf2f(phi));
        int ad = wv*1024 + prow*64 + (((key>>3)^(prow&7))<<3) + (key&7);
        lds[PHI+ad] = phi;
        lds[PLO+ad] = plo;
      }
    }

    #pragma unroll
    for (int kk=0; kk<2; ++kk){
      int ch = kk*4 + kgrp;
      int pr = lrow;
      short8 pah = *(const short8*)&lds[PHI + wv*1024 + pr*64 + ((ch^(pr&7))<<3)];
      short8 plo = *(const short8*)&lds[PLO + wv*1024 + pr*64 + ((ch^(pr&7))<<3)];
      #pragma unroll
      for (int j=0;j<4;j++){
        int vr = j*16 + lrow;
        int a0 = VT + vr*68 + ch*8;
        us4 p0 = *(const us4*)&lds[a0];
        us4 p1 = *(const us4*)&lds[a0+4];
        short8 bv_;
        #pragma unroll
        for (int e=0;e<4;e++){ bv_[e] = (short)p0[e]; bv_[4+e] = (short)p1[e]; }
        oacc[j] = mfma16(pah, bv_, oacc[j]);
        oacc[j] = mfma16(plo, bv_, oacc[j]);
      }
    }
    __syncthreads();
  }

  #pragma unroll
  for (int j=0;j<4;j++)
    #pragma unroll
    for (int r=0;r<4;r++){
      int rowl = bx*64 + wv*16 + kgrp*4 + r;
      Opart[(((size_t)(ck*64+z)*256 + rowl)*64) + j*16 + lrow] = oacc[j][r];
    }
  #pragma unroll
  for (int r=0;r<4;r++){
    if (lrow==0){
      int rowl = bx*64 + wv*16 + kgrp*4 + r;
      MLpart[((size_t)(ck*64+z)*256 + rowl)*2 + 0] = m_r[r];
      MLpart[((size_t)(ck*64+z)*256 + rowl)*2 + 1] = l_r[r];
    }
  }
}

// ---------- merged: o3c (blocks 0..63) + absmax (blocks 64..127) ----------
__global__ __launch_bounds__(256) void o3cab_k(const float* __restrict__ Opart,
    const float* __restrict__ MLpart, u16* __restrict__ O3Th, u16* __restrict__ O3Tl,
    const float* __restrict__ k2, float* __restrict__ mx)
{
  int t = threadIdx.x;
  if (blockIdx.x < 64){
    int z = blockIdx.x;
    float m[4], l[4];
    #pragma unroll
    for (int c=0;c<4;c++){
      m[c] = MLpart[((size_t)(c*64+z)*256 + t)*2 + 0];
      l[c] = MLpart[((size_t)(c*64+z)*256 + t)*2 + 1];
    }
    float M = fmaxf(fmaxf(m[0],m[1]), fmaxf(m[2],m[3]));
    float w[4]; float L = 0.f;
    #pragma unroll
    for (int c=0;c<4;c++){ w[c] = fexp(m[c]-M); L += l[c]*w[c]; }
    float inv = 1.0f/L;
    for (int d0=0; d0<16; ++d0){
      f32x4 o = (f32x4){0.f,0.f,0.f,0.f};
      #pragma unroll
      for (int c=0;c<4;c++){
        f32x4 x = *(const f32x4*)(Opart + ((size_t)(c*64+z)*256 + t)*64 + d0*4);
        #pragma unroll
        for (int e=0;e<4;e++) o[e] += w[c]*x[e];
      }
      #pragma unroll
      for (int e=0;e<4;e++){
        float val = o[e]*inv;
        int d = d0*4+e;
        u16 h = f2bf(val);
        O3Th[((size_t)z*64 + d)*256 + t] = h;
        O3Tl[((size_t)z*64 + d)*256 + t] = f2bf(val - bf2f(h));
      }
    }
  } else {
    int z = blockIdx.x - 64;
    const float* A = k2 + (size_t)z*65536;
    float rsum=0.f, csum=0.f;
    for (int j=0;j<256;j++){
      rsum += fabsf(A[t*256+j]);
      csum += fabsf(A[j*256+t]);
    }
    #pragma unroll
    for (int d=1; d<64; d<<=1){
      rsum = fmaxf(rsum, __shfl_xor(rsum, d));
      csum = fmaxf(csum, __shfl_xor(csum, d));
    }
    __shared__ float red[8];
    int wv=t>>6, ln=t&63;
    if (ln==0){ red[wv]=rsum; red[4+wv]=csum; }
    __syncthreads();
    if (t==0){
      float mr = fmaxf(fmaxf(red[0],red[1]),fmaxf(red[2],red[3]));
      float mc = fmaxf(fmaxf(red[4],red[5]),fmaxf(red[6],red[7]));
      atomicMax((int*)&mx[0], __float_as_int(mr));
      atomicMax((int*)&mx[1], __float_as_int(mc));
    }
  }
}

// ---------- small helpers ----------
__global__ void fill_k(float* __restrict__ p, int n, float v){
  for (int i = blockIdx.x*256 + threadIdx.x; i < n; i += gridDim.x*256) p[i] = v;
}
// merged setup+pool: prep (0..76) + wtr4 (77..1100) + wtrsplit2 (1101..1612) + pool (1613..2636)
__global__ __launch_bounds__(256) void setup_k(
    const float* __restrict__ mask, float* __restrict__ rs,
    const float* __restrict__ bq, const float* __restrict__ bk,
    const float* __restrict__ bv, float* __restrict__ bqkv, float* __restrict__ mx,
    const float* __restrict__ Wq, const float* __restrict__ Wk,
    const float* __restrict__ Wv, const float* __restrict__ Wff,
    u16* __restrict__ Tqkv, u16* __restrict__ Tff,
    u16* __restrict__ QH, u16* __restrict__ QL,
    u16* __restrict__ KH, u16* __restrict__ KL,
    const float* __restrict__ X,
    u16* __restrict__ Xlh, u16* __restrict__ Xll,
    float* __restrict__ ml, u16* __restrict__ Xb)
{
  __shared__ float t[64][65];
  int b = blockIdx.x;
  if (b < 77){
    if (b < 64){
      int i = b*256 + threadIdx.x;
      rs[i] = mask[i] * 0.3535533905932738f;
    } else if (b < 76){
      int j = (b-64)*256 + threadIdx.x;
      bqkv[j] = (j<1024) ? bq[j] : (j<2048) ? bk[j-1024] : bv[j-2048];
    } else {
      if (threadIdx.x < 2) mx[threadIdx.x] = 0.f;
    }
    return;
  }
  if (b >= 1613){
    int bl = b - 1613; int bb = bl>>8; int l = bl&255;
    const float* Xp = X + ((size_t)bb*4096 + (size_t)l*16)*1024;
    const float* mp = mask + (size_t)bb*4096 + (size_t)l*16;
    int tt = threadIdx.x;
    f32x4 acc = (f32x4){0.f,0.f,0.f,0.f};
    float msum = 0.f;
    #pragma unroll
    for (int j=0;j<16;j++){
      float mj = mp[j];
      msum += mj;
      f32x4 x = *(const f32x4*)(Xp + (size_t)j*1024 + tt*4);
      us4 xb;
      #pragma unroll
      for (int c=0;c<4;c++){ acc[c] += mj*x[c]; xb[c] = f2bf(x[c]); }
      *(us4*)(Xb + ((size_t)bl*16 + j)*1024 + tt*4) = xb;
    }
    const float c0 = 0.02209708691207961f;  // 1/(16*sqrt(sqrt(64)))
    us4 h, lo;
    #pragma unroll
    for (int c=0;c<4;c++){
      float v = acc[c]*c0;
      h[c] = f2bf(v);
      lo[c] = f2bf(v - bf2f(h[c]));
    }
    *(us4*)(Xlh + (size_t)bl*1024 + tt*4) = h;
    *(us4*)(Xll + (size_t)bl*1024 + tt*4) = lo;
    if (tt==0) ml[bl] = msum * c0;
    return;
  }
  int tt = threadIdx.x; int c = tt&63, r0 = tt>>6;
  if (b < 77+1024){
    int f = b - 77;
    int zi = f >> 8; int r2 = f & 255; int ti = r2 & 15; int tj = r2 >> 4;
    const float* W = (zi==0)?Wq:(zi==1)?Wk:(zi==2)?Wv:Wff;
    u16* T = (zi==3)? Tff : (Tqkv + (size_t)zi*1048576);
    #pragma unroll
    for (int rr=0; rr<16; rr++){
      int r = rr*4 + r0;
      t[r][c] = W[(size_t)(ti*64+r)*1024 + tj*64 + c];
    }
    __syncthreads();
    #pragma unroll
    for (int rr=0; rr<16; rr++){
      int r = rr*4 + r0;
      T[(size_t)(tj*64 + r)*1024 + ti*64 + c] = f2bf(t[c][r]);
    }
  } else {
    int f = b - 77 - 1024;
    int zi = f >> 8; int r2 = f & 255; int ti = r2 & 15; int tj = r2 >> 4;
    const float* W = zi ? Wk : Wq;
    u16* TH = zi ? KH : QH;
    u16* TL = zi ? KL : QL;
    #pragma unroll
    for (int rr=0; rr<16; rr++){
      int r = rr*4 + r0;
      t[r][c] = W[(size_t)(ti*64+r)*1024 + tj*64 + c];
    }
    __syncthreads();
    #pragma unroll
    for (int rr=0; rr<16; rr++){
      int r = rr*4 + r0;
      float v = t[c][r];
      u16 h = f2bf(v);
      TH[(size_t)(tj*64 + r)*1024 + ti*64 + c] = h;
      TL[(size_t)(tj*64 + r)*1024 + ti*64 + c] = f2bf(v - bf2f(h));
    }
  }
}
// K2f -> K2 row splits, V0 col splits (direct), V0 row splits (transposed)
__global__ __launch_bounds__(256) void v0prep_k(const float* __restrict__ K2f, const float* __restrict__ mx,
    u16* __restrict__ K2h, u16* __restrict__ K2l,
    u16* __restrict__ V0rh, u16* __restrict__ V0rl,
    u16* __restrict__ V0ch, u16* __restrict__ V0cl)
{
  int z = blockIdx.y; int bx = blockIdx.x;
  int ti = bx>>2, tj = bx&3;
  __shared__ float tile[64][65];
  const float* A = K2f + (size_t)z*65536;
  int t = threadIdx.x; int c = t&63, r0 = t>>6;
  float invden = 1.0f/(mx[0]*mx[1]);
  #pragma unroll
  for (int rr=0; rr<16; rr++){
    int r = rr*4 + r0;
    float v = A[(size_t)(ti*64 + r)*256 + tj*64 + c];
    tile[r][c] = v;
    size_t idx = (size_t)z*65536 + (size_t)(ti*64+r)*256 + tj*64 + c;
    u16 h = f2bf(v);
    K2h[idx] = h; K2l[idx] = f2bf(v - bf2f(h));
    float w = v*invden;
    h = f2bf(w);
    V0ch[idx] = h; V0cl[idx] = f2bf(w - bf2f(h));
  }
  __syncthreads();
  #pragma unroll
  for (int rr=0; rr<16; rr++){
    int r = rr*4 + r0;
    float w = tile[c][r]*invden;
    size_t idx = (size_t)z*65536 + (size_t)(tj*64+r)*256 + ti*64 + c;
    u16 h = f2bf(w);
    V0rh[idx] = h; V0rl[idx] = f2bf(w - bf2f(h));
  }
}

// fused attn = softmax(Qb @ Klb^T) @ tTb : all-bf16 operands, gld16 staging
__device__ __forceinline__ int swz64(int row,int k){
  return row*64 + (((((k>>3)&7) ^ (row&7)))<<3) + (k&7);
}
__device__ __forceinline__ int swz256(int row,int k){
  return row*256 + ((((k>>3) ^ (row&7)))<<3) + (k&7);
}
__global__ __launch_bounds__(256) void attn_k(const u16* __restrict__ Qb,
    const u16* __restrict__ Klb, const u16* __restrict__ tTb,
    u16* __restrict__ attn){
  __shared__ u16 lds[32768];
  const int z = blockIdx.y;
  const int rows0 = blockIdx.x * 64;
  const int tid = threadIdx.x;
  const int lane = tid & 63, wv = tid>>6;
  const int lrow = lane & 15, kgrp = lane>>4;
  const u16* Qz = Qb + ((size_t)z*4096 + rows0)*64;
  const u16* Klz = Klb + (size_t)z*16384;
  const u16* tTz = tTb + (size_t)z*16384;

  #pragma unroll
  for (int i=0;i<8;i++){
    int s = i*256 + tid;
    int row = s>>3, c = s&7;
    gld16(Klz + (size_t)row*64 + ((c^(row&7))<<3), lds + (s & ~63)*8);
  }
  #pragma unroll
  for (int i=0;i<2;i++){
    int s = i*256 + tid;
    int row = s>>3, c = s&7;
    gld16(Qz + (size_t)row*64 + ((c^(row&7))<<3), lds + 16384 + (s & ~63)*8);
  }
  __syncthreads();

  f32x4 acc[4][4];
  #pragma unroll
  for (int i=0;i<4;i++)
    #pragma unroll
    for (int j=0;j<4;j++) acc[i][j] = (f32x4){0.f,0.f,0.f,0.f};
  #pragma unroll
  for (int ks=0; ks<2; ++ks){
    int ko = ks*32 + kgrp*8;
    short8 a[4], b[4];
    #pragma unroll
    for (int i=0;i<4;i++) a[i] = *(const short8*)&lds[16384 + swz64(16*i+lrow, ko)];
    #pragma unroll
    for (int j=0;j<4;j++) b[j] = *(const short8*)&lds[swz64(wv*64 + j*16 + lrow, ko)];
    #pragma unroll
    for (int i=0;i<4;i++)
      #pragma unroll
      for (int j=0;j<4;j++) acc[i][j] = mfma16(a[i], b[j], acc[i][j]);
  }
  __syncthreads();   // Kl & Q dead

  #pragma unroll
  for (int i=0;i<8;i++){
    int s = i*256 + tid;
    int row = s>>5, c = s&31;
    int gch = (c & ~7) | ((c ^ row) & 7);
    gld16(tTz + (size_t)row*256 + (gch<<3), lds + 16384 + (s & ~63)*8);
  }

  float* r0 = (float*)lds;
  float* r1 = r0 + 256;
  #pragma unroll
  for (int i=0;i<4;i++)
    #pragma unroll
    for (int r=0;r<4;r++){
      float mx = fmaxf(fmaxf(acc[i][0][r], acc[i][1][r]), fmaxf(acc[i][2][r], acc[i][3][r]));
      #pragma unroll
      for (int d=1; d<16; d<<=1) mx = fmaxf(mx, __shfl_xor(mx, d));
      if (lrow==0) r0[(16*i + kgrp*4 + r)*4 + wv] = mx;
    }
  __syncthreads();
  float inv_ir[4][4];
  #pragma unroll
  for (int i=0;i<4;i++)
    #pragma unroll
    for (int r=0;r<4;r++){
      int row = 16*i + kgrp*4 + r;
      float gm = fmaxf(fmaxf(r0[row*4+0], r0[row*4+1]), fmaxf(r0[row*4+2], r0[row*4+3]));
      float s = 0.f;
      #pragma unroll
      for (int j=0;j<4;j++){
        acc[i][j][r] = fexp(acc[i][j][r] - gm);
        s += acc[i][j][r];
      }
      #pragma unroll
      for (int d=1; d<16; d<<=1) s += __shfl_xor(s, d);
      if (lrow==0) r1[row*4 + wv] = s;
      inv_ir[i][r] = 0.f; (void)inv_ir;
    }
  __syncthreads();
  #pragma unroll
  for (int i=0;i<4;i++)
    #pragma unroll
    for (int r=0;r<4;r++){
      int row = 16*i + kgrp*4 + r;
      inv_ir[i][r] = 1.0f/(r1[row*4+0]+r1[row*4+1]+r1[row*4+2]+r1[row*4+3]);
    }
  __syncthreads();

  #pragma unroll
  for (int i=0;i<4;i++)
    #pragma unroll
    for (int j=0;j<4;j++)
      #pragma unroll
      for (int r=0;r<4;r++){
        int row = 16*i + kgrp*4 + r;
        int l = wv*64 + j*16 + lrow;
        lds[swz256(row, l)] = f2bf(acc[i][j][r]*inv_ir[i][r]);
      }
  __syncthreads();   // also drains tT gld16

  f32x4 o[4];
  #pragma unroll
  for (int j=0;j<4;j++) o[j] = (f32x4){0.f,0.f,0.f,0.f};
  #pragma unroll
  for (int ks=0; ks<8; ++ks){
    int ko = ks*32 + kgrp*8;
    short8 a = *(const short8*)&lds[swz256(16*wv + lrow, ko)];
    #pragma unroll
    for (int j=0;j<4;j++){
      short8 bb = *(const short8*)&lds[16384 + swz256(j*16 + lrow, ko)];
      o[j] = mfma16(a, bb, o[j]);
    }
  }
  __syncthreads();
  #pragma unroll
  for (int j=0;j<4;j++)
    #pragma unroll
    for (int r=0;r<4;r++){
      int m = 16*wv + kgrp*4 + r;
      lds[m*64 + j*16 + lrow] = f2bf(o[j][r]);
    }
  __syncthreads();
  int b = z>>4, h = z&15;
  #pragma unroll
  for (int c=0;c<2;c++){
    int idx = c*256 + tid;
    int row = idx >> 3;
    int seg = idx & 7;
    us8 v = *(const us8*)&lds[row*64 + seg*8];
    *(us8*)&attn[((size_t)b*4096 + rows0 + row)*1024 + (size_t)h*64 + seg*8] = v;
  }
}

extern "C" void kernel_launch(void* const* d_in, const int* in_sizes, int n_in,
                              void* d_out, int out_size, void* d_ws, size_t ws_size,
                              hipStream_t stream) {
  (void)in_sizes; (void)n_in;
  const float* X    = (const float*)d_in[0];
  const float* mask = (const float*)d_in[1];
  const float* Wq   = (const float*)d_in[2];
  const float* bq   = (const float*)d_in[3];
  const float* Wk   = (const float*)d_in[4];
  const float* bk   = (const float*)d_in[5];
  const float* Wv   = (const float*)d_in[6];
  const float* bv   = (const float*)d_in[7];
  const float* Wff  = (const float*)d_in[8];
  const float* bff  = (const float*)d_in[9];
  float* outp = (float*)d_out;
  char* ws = (char*)d_ws;

  auto MiB = [](size_t x){ return x<<20; };
  // ---- static layout ----
  const size_t O_QB   = 0;
  const size_t O_KB   = MiB(32);
  const size_t O_VB   = MiB(64);
  const size_t O_XB   = MiB(96);
  const size_t O_RG[4][2] = {
    {MiB(32),MiB(40)}, {MiB(48),MiB(56)}, {MiB(64),MiB(72)}, {MiB(80),MiB(88)} };
  const size_t O_QLH  = MiB(96),  O_QLL = MiB(98), O_KLL = MiB(100);
  const size_t O_OPART= MiB(96);
  const size_t O_MLP  = MiB(112);
  const size_t O_XAH  = MiB(96),  O_XAL = MiB(104);
  const size_t O_K2H  = MiB(112), O_K2L = MiB(120);
  const size_t O_K2F  = MiB(128);
  const size_t O_WQKVT= MiB(128);
  const size_t O_XLH  = MiB(134), O_XLL = MiB(136);
  const size_t O_WQTH = MiB(138), O_WQTL = MiB(140);
  const size_t O_QL   = MiB(144);
  const size_t O_TTB  = MiB(144);
  const size_t O_KL   = MiB(148);
  const size_t O_O3TH = MiB(152), O_O3TL = MiB(154);
  const size_t O_WKTH = MiB(152), O_WKTL = MiB(154);
  const size_t O_WFFT = MiB(156);
  const size_t O_KLB  = MiB(158);
  const size_t O_ATTN = MiB(32);
  const size_t O_RS   = MiB(162);
  const size_t O_ML   = O_RS + 65536;
  const size_t O_MX   = O_ML + 4096;
  const size_t O_BQKV = O_MX + 256;
  const size_t NEED   = O_BQKV + 16384;

  if (ws_size < NEED){
    fill_k<<<2048,256,0,stream>>>(outp, out_size, 1.0e9f);
    return;
  }

  u16*   Qb   = (u16*)(ws + O_QB);
  u16*   Kb   = (u16*)(ws + O_KB);
  u16*   Vb   = (u16*)(ws + O_VB);
  u16*   Xb   = (u16*)(ws + O_XB);
  u16*   WqkvT= (u16*)(ws + O_WQKVT);
  u16*   WffT = (u16*)(ws + O_WFFT);
  float* bqkv = (float*)(ws + O_BQKV);
  float* Ql   = (float*)(ws + O_QL);
  float* Kl   = (float*)(ws + O_KL);
  u16*   QlH  = (u16*)(ws + O_QLH);
  u16*   QlL  = (u16*)(ws + O_QLL);
  u16*   KlL  = (u16*)(ws + O_KLL);
  u16*   Klb  = (u16*)(ws + O_KLB);
  u16*   tTb  = (u16*)(ws + O_TTB);
  float* K2f  = (float*)(ws + O_K2F);
  float* rs   = (float*)(ws + O_RS);
  float* ml   = (float*)(ws + O_ML);
  float* Mx   = (float*)(ws + O_MX);
  float* Opart= (float*)(ws + O_OPART);
  float* MLp  = (float*)(ws + O_MLP);
  u16*   O3Th = (u16*)(ws + O_O3TH);
  u16*   O3Tl = (u16*)(ws + O_O3TL);
  u16*   K2h  = (u16*)(ws + O_K2H);
  u16*   K2l  = (u16*)(ws + O_K2L);
  u16*   XAh  = (u16*)(ws + O_XAH);
  u16*   XAl  = (u16*)(ws + O_XAL);
  u16*   Xlh  = (u16*)(ws + O_XLH);
  u16*   Xll  = (u16*)(ws + O_XLL);
  u16*   WqTh = (u16*)(ws + O_WQTH);
  u16*   WqTl = (u16*)(ws + O_WQTL);
  u16*   WkTh = (u16*)(ws + O_WKTH);
  u16*   WkTl = (u16*)(ws + O_WKTL);
  u16*   AttnB= (u16*)(ws + O_ATTN);
  u16* RGH[4]; u16* RGL[4];
  for (int i=0;i<4;i++){ RGH[i] = (u16*)(ws + O_RG[i][0]); RGL[i] = (u16*)(ws + O_RG[i][1]); }

  // merged prep + weight transposes + pool
  setup_k<<<2637,256,0,stream>>>(mask, rs, bq, bk, bv, bqkv, Mx,
      Wq, Wk, Wv, Wff, WqkvT, WffT, WqTh, WqTl, WkTh, WkTl,
      X, Xlh, Xll, ml, Xb);

  // fused QKV projection (256x128 tile, 8-wave blocks)
  fgemm_k<1><<<dim3(24,64),512,0,stream>>>(Xb, WqkvT, nullptr, Qb, Kb, Vb,
      16384, 3072, 1024, 24, bqkv, rs);

  // landmarks (split): Ql/Kl = Xl@W + ml*b; also emit hi/lo split images
  sgemm_k<2><<<dim3(16,16,1),256,0,stream>>>(Xlh, Xll, WqTh, WqTl, 1024, 0, 0,
      QlH, QlL, nullptr, nullptr, Ql, 0, 0, 0.f, 0.f, 1.f, bq, ml);
  sgemm_k<2><<<dim3(16,16,1),256,0,stream>>>(Xlh, Xll, WkTh, WkTl, 1024, 0, 0,
      Klb, KlL, nullptr, nullptr, Kl, 0, 0, 0.f, 0.f, 1.f, bk, ml);

  // k2 = softmax(Ql@Kl^T) -> f32 (split-staged)
  k2s_k<<<dim3(4,64),256,0,stream>>>(QlH, QlL, Klb, KlL, K2f);

  // O3 partials (flash, KV split x4) + merged combine+absmax
  o3p_k<<<dim3(4,4,64),256,0,stream>>>(Ql, Kb, Vb, mask, Opart, MLp);
  o3cab_k<<<128,256,0,stream>>>(Opart, MLp, O3Th, O3Tl, K2f, Mx);

  // Newton-Schulz pseudo-inverse of k2 (pre-split operands, region rotation)
  v0prep_k<<<dim3(16,64),256,0,stream>>>(K2f, Mx, K2h, K2l, RGH[1], RGL[1], RGH[0], RGL[0]);
  int vc=0, vr=1, kv=2, x2=3;
  for (int it=0; it<6; ++it){
    sgemm_k<0><<<dim3(4,4,64),256,0,stream>>>(K2h, K2l, RGH[vc], RGL[vc], 256, 65536, 65536,
        RGH[kv], RGL[kv], XAh, XAl, nullptr, 0, 0, 7.f, -1.f, 1.f, nullptr, nullptr);
    sgemm_k<0><<<dim3(4,4,64),256,0,stream>>>(RGH[kv], RGL[kv], XAh, XAl, 256, 65536, 65536,
        nullptr, nullptr, RGH[x2], RGL[x2], nullptr, 0, 0, 15.f, -1.f, 1.f, nullptr, nullptr);
    sgemm_k<0><<<dim3(4,4,64),256,0,stream>>>(RGH[kv], RGL[kv], RGH[x2], RGL[x2], 256, 65536, 65536,
        nullptr, nullptr, XAh, XAl, nullptr, 0, 0, 13.f, -1.f, 1.f, nullptr, nullptr);
    sgemm_k<0><<<dim3(4,4,64),256,0,stream>>>(RGH[vr], RGL[vr], XAh, XAl, 256, 65536, 65536,
        RGH[kv], RGL[kv], RGH[x2], RGL[x2], nullptr, 0, 0, 0.f, 1.f, 0.25f, nullptr, nullptr);
    int nvc=x2, nvr=kv, nkv=vc, nx2=vr;
    vc=nvc; vr=nvr; kv=nkv; x2=nx2;
  }
  // t = Vfinal @ O3 -> tT bf16 [z][64][256] directly
  sgemm_k<1><<<dim3(4,1,64),256,0,stream>>>(RGH[vr], RGL[vr], O3Th, O3Tl, 256, 65536, 16384,
      nullptr,nullptr, tTb, nullptr, nullptr, 0, 0, 0.f, 0.f, 1.f, nullptr, nullptr);

  // attn = softmax(Qb@Klb^T)@tTb -> bf16 [b][s][h*64+d]
  attn_k<<<dim3(64,64),256,0,stream>>>(Qb, Klb, tTb, AttnB);

  // out = attn @ Wff + bff -> f32 (256x128 tile, 8-wave blocks)
  fgemm_k<0><<<dim3(8,64),512,0,stream>>>(AttnB, WffT, outp, nullptr, nullptr, nullptr,
      16384, 1024, 1024, 8, bff, nullptr);
}

// Round 19
// 951.395 us; speedup vs baseline: 1.0483x; 1.0483x over previous
//
#include <hip/hip_runtime.h>
#include <cstdint>
#include <cstddef>

// Nystromformer attention block for MI355X (gfx950).
// B=4, S=4096, DIM=1024, H=16, D=64, m=256 landmarks.

typedef unsigned short u16;
typedef __attribute__((ext_vector_type(8))) short short8;
typedef __attribute__((ext_vector_type(4))) float f32x4;
typedef __attribute__((ext_vector_type(4))) unsigned short us4;
typedef __attribute__((ext_vector_type(8))) unsigned short us8;

__device__ __forceinline__ float bf2f(u16 u){ return __uint_as_float(((unsigned int)u)<<16); }
__device__ __forceinline__ u16 f2bf(float x){
  unsigned int i = __float_as_uint(x);
  unsigned int r = i + 0x7FFFu + ((i>>16)&1u);   // RNE
  return (u16)(r>>16);
}
__device__ __forceinline__ f32x4 mfma16(short8 a, short8 b, f32x4 c){
  return __builtin_amdgcn_mfma_f32_16x16x32_bf16(a,b,c,0,0,0);
}
__device__ __forceinline__ void gld16(const void* g, void* l){
  __builtin_amdgcn_global_load_lds(
      (const __attribute__((address_space(1))) unsigned int*)g,
      (__attribute__((address_space(3))) unsigned int*)l, 16, 0, 0);
}
// native exp (v_exp_f32): ~3 VALU inst vs ~15 for libm expf; ~2ulp accuracy
__device__ __forceinline__ float fexp(float x){ return __expf(x); }

// ---------- k2 = softmax(Ql @ Kl^T) from pre-split hi/lo operands ----------
__global__ __launch_bounds__(256) void k2s_k(
    const u16* __restrict__ Ah, const u16* __restrict__ Al,
    const u16* __restrict__ Bh, const u16* __restrict__ Bl,
    float* __restrict__ C)
{
  __shared__ u16 lds[40960];   // Ah@0(4096) Al@4096 Bh@8192(16384) Bl@24576
  const int tid = threadIdx.x;
  const int tileM = blockIdx.x*64;
  const int z = blockIdx.y;
  const int lane = tid&63, wv = tid>>6;
  const int lrow = lane&15, kgrp = lane>>4;
  const u16* baseAh = Ah + (size_t)z*16384 + (size_t)tileM*64;
  const u16* baseAl = Al + (size_t)z*16384 + (size_t)tileM*64;
  const u16* baseBh = Bh + (size_t)z*16384;
  const u16* baseBl = Bl + (size_t)z*16384;

  #pragma unroll
  for (int it=0; it<2; ++it){
    int w = it*256 + tid; int row = w>>3, c = w&7; int cs = c^(row&7);
    gld16(baseAh + (size_t)row*64 + (cs<<3), lds + (w & ~63)*8);
  }
  #pragma unroll
  for (int it=0; it<2; ++it){
    int w = it*256 + tid; int row = w>>3, c = w&7; int cs = c^(row&7);
    gld16(baseAl + (size_t)row*64 + (cs<<3), lds + 4096 + (w & ~63)*8);
  }
  #pragma unroll
  for (int it=0; it<8; ++it){
    int w = it*256 + tid; int row = w>>3, c = w&7; int cs = c^(row&7);
    gld16(baseBh + (size_t)row*64 + (cs<<3), lds + 8192 + (w & ~63)*8);
  }
  #pragma unroll
  for (int it=0; it<8; ++it){
    int w = it*256 + tid; int row = w>>3, c = w&7; int cs = c^(row&7);
    gld16(baseBl + (size_t)row*64 + (cs<<3), lds + 24576 + (w & ~63)*8);
  }
  __syncthreads();

  f32x4 acc[16];
  #pragma unroll
  for (int j=0;j<16;j++) acc[j] = (f32x4){0.f,0.f,0.f,0.f};

  #pragma unroll
  for (int kt=0; kt<2; ++kt){
    int ch = kt*4 + kgrp;
    int ra = wv*16 + lrow;
    short8 ah = *(const short8*)&lds[ra*64 + ((ch^(ra&7))<<3)];
    short8 al = *(const short8*)&lds[4096 + ra*64 + ((ch^(ra&7))<<3)];
    #pragma unroll
    for (int j=0;j<16;j++){
      int rb = j*16 + lrow;
      short8 bh = *(const short8*)&lds[8192 + rb*64 + ((ch^(rb&7))<<3)];
      short8 bl = *(const short8*)&lds[24576 + rb*64 + ((ch^(rb&7))<<3)];
      acc[j] = mfma16(ah, bh, acc[j]);
      acc[j] = mfma16(ah, bl, acc[j]);
      acc[j] = mfma16(al, bh, acc[j]);
    }
  }

  float* Cz = C + (size_t)z*65536;
  #pragma unroll
  for (int r=0;r<4;r++){
    float mx = -3.0e38f;
    #pragma unroll
    for (int j=0;j<16;j++) mx = fmaxf(mx, acc[j][r]);
    #pragma unroll
    for (int d=1; d<16; d<<=1) mx = fmaxf(mx, __shfl_xor(mx, d));
    float p[16]; float ss = 0.f;
    #pragma unroll
    for (int j=0;j<16;j++){ p[j] = fexp(acc[j][r]-mx); ss += p[j]; }
    #pragma unroll
    for (int d=1; d<16; d<<=1) ss += __shfl_xor(ss, d);
    float inv = 1.0f/ss;
    int row = tileM + wv*16 + kgrp*4 + r;
    #pragma unroll
    for (int j=0;j<16;j++){
      int col = j*16 + lrow;
      Cz[(size_t)row*256 + col] = p[j]*inv;
    }
  }
}

// ---------- pre-split bf16 GEMM: C = A[M,K] * B^T with A,B as hi/lo pairs ----------
// OUT 0: Newton epilogue. OUT 1: tT bf16 transpose out. OUT 2: f32 landmark scatter.
template<int OUT>
__global__ __launch_bounds__(256) void sgemm_k(
    const u16* __restrict__ Ah, const u16* __restrict__ Al,
    const u16* __restrict__ Bh, const u16* __restrict__ Bl,
    int K, long long sA, long long sB,
    u16* __restrict__ RoH, u16* __restrict__ RoL,
    u16* __restrict__ CoH, u16* __restrict__ CoL,
    float* __restrict__ Fo, long long sO, int ldO,
    float addI, float csgn, float scale,
    const float* __restrict__ bias, const float* __restrict__ ml)
{
  __shared__ u16 lds[16384];
  const int tid = threadIdx.x;
  const int z = blockIdx.z;
  const int tileM = blockIdx.x*64, tileN = blockIdx.y*64;
  const int lane = tid&63, wv = tid>>6;
  const int wr = wv>>1, wc = wv&1;
  const int lrow = lane&15, kgrp = lane>>4;

  const u16* __restrict__ base[4] = {
    Ah + (size_t)z*sA + (size_t)tileM*K,
    Al + (size_t)z*sA + (size_t)tileM*K,
    Bh + (size_t)z*sB + (size_t)tileN*K,
    Bl + (size_t)z*sB + (size_t)tileN*K };

  f32x4 acc[2][2];
  #pragma unroll
  for (int i=0;i<2;i++)
    #pragma unroll
    for (int j=0;j<2;j++) acc[i][j] = (f32x4){0.f,0.f,0.f,0.f};

  for (int k0=0; k0<K; k0+=64){
    #pragma unroll
    for (int t4=0; t4<4; ++t4){
      #pragma unroll
      for (int hf=0; hf<2; ++hf){
        int w = hf*256 + tid;
        int row = w>>3, c = w&7;
        int cs = c ^ (row&7);
        gld16(base[t4] + (size_t)row*K + k0 + cs*8, lds + t4*4096 + (w & ~63)*8);
      }
    }
    __syncthreads();
    #pragma unroll
    for (int kk=0; kk<2; ++kk){
      int ch = kk*4 + kgrp;
      short8 a_h[2], a_l[2], b_h[2], b_l[2];
      #pragma unroll
      for (int i=0;i<2;i++){
        int r = wr*32 + i*16 + lrow;
        int off = r*64 + ((ch ^ (r&7))<<3);
        a_h[i] = *(const short8*)&lds[off];
        a_l[i] = *(const short8*)&lds[4096 + off];
      }
      #pragma unroll
      for (int j=0;j<2;j++){
        int r = wc*32 + j*16 + lrow;
        int off = r*64 + ((ch ^ (r&7))<<3);
        b_h[j] = *(const short8*)&lds[8192 + off];
        b_l[j] = *(const short8*)&lds[12288 + off];
      }
      #pragma unroll
      for (int i=0;i<2;i++)
        #pragma unroll
        for (int j=0;j<2;j++){
          acc[i][j] = mfma16(a_h[i], b_h[j], acc[i][j]);
          acc[i][j] = mfma16(a_h[i], b_l[j], acc[i][j]);
          acc[i][j] = mfma16(a_l[i], b_h[j], acc[i][j]);
        }
    }
    __syncthreads();
  }

  if constexpr (OUT==0 || OUT==1){
    #pragma unroll
    for (int i=0;i<2;i++)
      #pragma unroll
      for (int j=0;j<2;j++){
        int rl0 = wr*32 + i*16 + kgrp*4;
        int cl  = wc*32 + j*16 + lrow;
        #pragma unroll
        for (int q=0;q<4;q++){
          int rl = rl0 + q;
          float p = acc[i][j][q]*scale;
          if constexpr (OUT==0){
            if (RoH){
              u16 h = f2bf(p);
              int lo = rl*64 + (cl ^ ((rl&7)<<3));
              lds[lo] = h;
              lds[4096 + lo] = f2bf(p - bf2f(h));
            }
            float cv = csgn*p + (((tileM+rl)==(tileN+cl))? addI : 0.f);
            u16 ch = f2bf(cv);
            int lo2 = cl*64 + (rl ^ ((cl&7)<<3));
            lds[8192 + lo2] = ch;
            lds[12288 + lo2] = f2bf(cv - bf2f(ch));
          } else {
            lds[cl*64 + (rl ^ ((cl&7)<<3))] = f2bf(p);
          }
        }
      }
    __syncthreads();
    if constexpr (OUT==0){
      if (RoH){
        #pragma unroll
        for (int c2=0;c2<2;c2++){
          int idx = c2*256 + tid;
          int row = idx>>3, seg = idx&7;
          int lo = row*64 + ((seg ^ (row&7))<<3);
          size_t go = (size_t)z*65536 + (size_t)(tileM+row)*256 + tileN + seg*8;
          *(us8*)&RoH[go] = *(const us8*)&lds[lo];
          *(us8*)&RoL[go] = *(const us8*)&lds[4096 + lo];
        }
      }
      #pragma unroll
      for (int c2=0;c2<2;c2++){
        int idx = c2*256 + tid;
        int row = idx>>3, seg = idx&7;
        int lo = row*64 + ((seg ^ (row&7))<<3);
        size_t go = (size_t)z*65536 + (size_t)(tileN+row)*256 + tileM + seg*8;
        *(us8*)&CoH[go] = *(const us8*)&lds[8192 + lo];
        *(us8*)&CoL[go] = *(const us8*)&lds[12288 + lo];
      }
    } else {
      #pragma unroll
      for (int c2=0;c2<2;c2++){
        int idx = c2*256 + tid;
        int row = idx>>3, seg = idx&7;
        int lo = row*64 + ((seg ^ (row&7))<<3);
        *(us8*)&CoH[(size_t)z*16384 + (size_t)(tileN+row)*256 + tileM + seg*8] =
            *(const us8*)&lds[lo];
      }
    }
  } else {
    #pragma unroll
    for (int i=0;i<2;i++)
      #pragma unroll
      for (int j=0;j<2;j++){
        int grow0 = tileM + wr*32 + i*16 + kgrp*4;
        int gcol  = tileN + wc*32 + j*16 + lrow;
        #pragma unroll
        for (int q=0;q<4;q++){
          int grow = grow0+q;
          float v = acc[i][j][q] + ml[grow]*bias[gcol];
          int b = grow>>8, l = grow&255, h = gcol>>6, d = gcol&63;
          size_t oi = (((size_t)(b*16+h)*256 + l)*64 + d);
          Fo[oi] = v;
          if (RoH){
            u16 hh = f2bf(v);
            RoH[oi] = hh;
            RoL[oi] = f2bf(v - bf2f(hh));
          }
        }
      }
  }
}

// ---------- fast bf16 GEMM: 128x128 tile, 8 waves (512 thr), wave tile 64x32 ----------
// EPI 0: f32 row-major out. EPI 1: QKV scatter via LDS-bounce.
template<int EPI>
__global__ __launch_bounds__(512) void fgemm_k(
    const u16* __restrict__ A, const u16* __restrict__ Bt, float* __restrict__ Cf,
    u16* __restrict__ Q_, u16* __restrict__ K_, u16* __restrict__ V_,
    int M, int N, int K, int nTilesN,
    const float* __restrict__ bias, const float* __restrict__ rowscale)
{
  __shared__ u16 lds[2*128*64];
  u16* ldsA = lds;
  u16* ldsB = lds + 128*64;

  int flat = blockIdx.y*nTilesN + blockIdx.x;
  int nwg  = gridDim.x*gridDim.y;
  int chunk = nwg >> 3;
  int nid = (flat & 7)*chunk + (flat >> 3);
  int bxM = nid / nTilesN, byN = nid % nTilesN;
  const int tileM = bxM*128, tileN = byN*128;

  const int tid = threadIdx.x;
  const int lane = tid & 63, wv = tid>>6;
  const int wr = wv>>2, wc = wv&3;          // 2 x 4 wave grid, wave tile 64x32
  const int lrow = lane&15, kgrp = lane>>4;

  f32x4 acc[4][2];
  #pragma unroll
  for (int i=0;i<4;i++)
    #pragma unroll
    for (int j=0;j<2;j++) acc[i][j] = (f32x4){0.f,0.f,0.f,0.f};

  for (int k0=0; k0<K; k0+=64){
    #pragma unroll
    for (int i=0;i<2;i++){
      int s = i*512 + tid;
      int row = s>>3, c = s&7;
      int cs = c ^ (row&7);
      gld16(A + (size_t)(tileM+row)*K + k0 + cs*8, ldsA + (size_t)(s & ~63)*8);
    }
    #pragma unroll
    for (int i=0;i<2;i++){
      int s = i*512 + tid;
      int row = s>>3, c = s&7;
      int cs = c ^ (row&7);
      gld16(Bt + (size_t)(tileN+row)*K + k0 + cs*8, ldsB + (size_t)(s & ~63)*8);
    }
    __syncthreads();
    #pragma unroll
    for (int kk=0; kk<2; ++kk){
      int ch = kk*4 + kgrp;
      short8 af[4], bf[2];
      #pragma unroll
      for (int i=0;i<4;i++){
        int r = wr*64 + i*16 + lrow;
        af[i] = *(const short8*)&ldsA[r*64 + ((ch^(r&7))<<3)];
      }
      #pragma unroll
      for (int j=0;j<2;j++){
        int r = wc*32 + j*16 + lrow;
        bf[j] = *(const short8*)&ldsB[r*64 + ((ch^(r&7))<<3)];
      }
      #pragma unroll
      for (int i=0;i<4;i++)
        #pragma unroll
        for (int j=0;j<2;j++)
          acc[i][j] = mfma16(af[i], bf[j], acc[i][j]);
    }
    __syncthreads();
  }

  if constexpr (EPI==0){
    #pragma unroll
    for (int i=0;i<4;i++)
      #pragma unroll
      for (int j=0;j<2;j++)
        #pragma unroll
        for (int q=0;q<4;q++){
          int row = tileM + wr*64 + i*16 + kgrp*4 + q;
          int col = tileN + wc*32 + j*16 + lrow;
          Cf[(size_t)row*N + col] = acc[i][j][q] + (bias ? bias[col] : 0.f);
        }
  } else {
    #pragma unroll
    for (int i=0;i<4;i++)
      #pragma unroll
      for (int j=0;j<2;j++)
        #pragma unroll
        for (int q=0;q<4;q++){
          int rloc = wr*64 + i*16 + kgrp*4 + q;
          int cloc = wc*32 + j*16 + lrow;
          int col = tileN + cloc;
          float v = acc[i][j][q] + bias[col];
          if ((col>>10) < 2) v *= rowscale[tileM + rloc];
          lds[rloc*128 + cloc] = f2bf(v);
        }
    __syncthreads();
    #pragma unroll
    for (int c=0;c<4;c++){
      int idx = c*512 + tid;
      int row = idx >> 4;       // 0..127
      int seg = idx & 15;       // 0..15 (8 elems each)
      int col = tileN + seg*8;
      int which = col >> 10;
      int hd = col & 1023, h = hd>>6, d0 = hd&63;
      int grow = tileM + row;
      int b = grow>>12, s = grow&4095;
      u16* dst = (which==0) ? Q_ : (which==1) ? K_ : V_;
      us8 v = *(const us8*)&lds[row*128 + seg*8];
      *(us8*)&dst[(((size_t)(b*16+h))*4096 + s)*64 + d0] = v;
    }
  }
}

// ---------- flash O3 partials: chunked softmax(Ql @ K^T + maskbias) @ V ----------
__global__ __launch_bounds__(256) void o3p_k(
    const float* __restrict__ Ql, const u16* __restrict__ Kb, const u16* __restrict__ Vb,
    const float* __restrict__ mask, float* __restrict__ Opart, float* __restrict__ MLpart)
{
  constexpr int QHI=0, QLO=4096, KT=8192, VT=12288, PHI=16640, PLO=20736;
  __shared__ u16 lds[24832];
  const int bx = blockIdx.x, ck = blockIdx.y, z = blockIdx.z;
  const int tid = threadIdx.x;
  const int lane = tid&63, wv = tid>>6;
  const int lrow = lane&15, kgrp = lane>>4;
  const float* Qlz = Ql + (size_t)z*16384 + (size_t)bx*64*64;
  const u16* Kz = Kb + (size_t)z*4096*64;
  const u16* Vz = Vb + (size_t)z*4096*64;
  const float* mrow = mask + (size_t)(z>>4)*4096;

  #pragma unroll
  for (int i=0;i<2;i++){
    int s = i*256 + tid;
    int row = s>>3, c = s&7;
    const float* src = Qlz + row*64 + c*8;
    f32x4 v0 = *(const f32x4*)src;
    f32x4 v1 = *(const f32x4*)(src+4);
    us8 hi, lo;
    #pragma unroll
    for (int e=0;e<4;e++){
      hi[e] = f2bf(v0[e]); lo[e] = f2bf(v0[e]-bf2f(hi[e]));
      hi[4+e] = f2bf(v1[e]); lo[4+e] = f2bf(v1[e]-bf2f(hi[4+e]));
    }
    int ad = row*64 + ((c^(row&7))<<3);
    *(us8*)&lds[QHI+ad] = hi;
    *(us8*)&lds[QLO+ad] = lo;
  }

  float m_r[4], l_r[4];
  f32x4 oacc[4];
  #pragma unroll
  for (int r=0;r<4;r++){ m_r[r] = -3.0e38f; l_r[r] = 0.f; }
  #pragma unroll
  for (int j=0;j<4;j++) oacc[j] = (f32x4){0.f,0.f,0.f,0.f};

  for (int st=0; st<16; ++st){
    int s0 = (ck*16 + st)*64;
    #pragma unroll
    for (int i=0;i<2;i++){
      int s = i*256 + tid;
      int row = s>>3, c = s&7;
      int cs = c ^ (row&7);
      gld16(Kz + (size_t)(s0+row)*64 + cs*8, &lds[KT + (size_t)(s & ~63)*8]);
    }
    #pragma unroll
    for (int i=0;i<2;i++){
      int s = i*256 + tid;
      int row = s>>3, c = s&7;
      us8 v = *(const us8*)(Vz + (size_t)(s0+row)*64 + c*8);
      #pragma unroll
      for (int e=0;e<8;e++) lds[VT + (c*8+e)*68 + row] = v[e];
    }
    __syncthreads();

    f32x4 sacc[4];
    #pragma unroll
    for (int j=0;j<4;j++) sacc[j] = (f32x4){0.f,0.f,0.f,0.f};
    int qr = wv*16 + lrow;
    #pragma unroll
    for (int kk=0; kk<2; ++kk){
      int ch = kk*4 + kgrp;
      short8 ah = *(const short8*)&lds[QHI + qr*64 + ((ch^(qr&7))<<3)];
      short8 alo = *(const short8*)&lds[QLO + qr*64 + ((ch^(qr&7))<<3)];
      #pragma unroll
      for (int j=0;j<4;j++){
        int kr = j*16 + lrow;
        short8 bk = *(const short8*)&lds[KT + kr*64 + ((ch^(kr&7))<<3)];
        sacc[j] = mfma16(ah, bk, sacc[j]);
        sacc[j] = mfma16(alo, bk, sacc[j]);
      }
    }
    float mb[4];
    #pragma unroll
    for (int j=0;j<4;j++) mb[j] = -1.0e9f*(1.0f - mrow[s0 + j*16 + lrow]);
    #pragma unroll
    for (int j=0;j<4;j++)
      #pragma unroll
      for (int r=0;r<4;r++) sacc[j][r] += mb[j];

    #pragma unroll
    for (int r=0;r<4;r++){
      float tm = fmaxf(fmaxf(sacc[0][r],sacc[1][r]), fmaxf(sacc[2][r],sacc[3][r]));
      #pragma unroll
      for (int d=1; d<16; d<<=1) tm = fmaxf(tm, __shfl_xor(tm, d));
      float mn = fmaxf(m_r[r], tm);
      float scf = fexp(m_r[r] - mn);
      float ps[4]; float tsum = 0.f;
      #pragma unroll
      for (int j=0;j<4;j++){ ps[j] = fexp(sacc[j][r] - mn); tsum += ps[j]; }
      #pragma unroll
      for (int d=1; d<16; d<<=1) tsum += __shfl_xor(tsum, d);
      l_r[r] = l_r[r]*scf + tsum;
      m_r[r] = mn;
      #pragma unroll
      for (int j=0;j<4;j++) oacc[j][r] *= scf;
      int prow = kgrp*4 + r;
      #pragma unroll
      for (int j=0;j<4;j++){
        int key = j*16 + lrow;
        u16 phi = f2bf(ps[j]);
        u16 plo = f2bf(ps[j] - bf2f(phi));
        int ad = wv*1024 + prow*64 + (((key>>3)^(prow&7))<<3) + (key&7);
        lds[PHI+ad] = phi;
        lds[PLO+ad] = plo;
      }
    }

    #pragma unroll
    for (int kk=0; kk<2; ++kk){
      int ch = kk*4 + kgrp;
      int pr = lrow;
      short8 pah = *(const short8*)&lds[PHI + wv*1024 + pr*64 + ((ch^(pr&7))<<3)];
      short8 plo = *(const short8*)&lds[PLO + wv*1024 + pr*64 + ((ch^(pr&7))<<3)];
      #pragma unroll
      for (int j=0;j<4;j++){
        int vr = j*16 + lrow;
        int a0 = VT + vr*68 + ch*8;
        us4 p0 = *(const us4*)&lds[a0];
        us4 p1 = *(const us4*)&lds[a0+4];
        short8 bv_;
        #pragma unroll
        for (int e=0;e<4;e++){ bv_[e] = (short)p0[e]; bv_[4+e] = (short)p1[e]; }
        oacc[j] = mfma16(pah, bv_, oacc[j]);
        oacc[j] = mfma16(plo, bv_, oacc[j]);
      }
    }
    __syncthreads();
  }

  #pragma unroll
  for (int j=0;j<4;j++)
    #pragma unroll
    for (int r=0;r<4;r++){
      int rowl = bx*64 + wv*16 + kgrp*4 + r;
      Opart[(((size_t)(ck*64+z)*256 + rowl)*64) + j*16 + lrow] = oacc[j][r];
    }
  #pragma unroll
  for (int r=0;r<4;r++){
    if (lrow==0){
      int rowl = bx*64 + wv*16 + kgrp*4 + r;
      MLpart[((size_t)(ck*64+z)*256 + rowl)*2 + 0] = m_r[r];
      MLpart[((size_t)(ck*64+z)*256 + rowl)*2 + 1] = l_r[r];
    }
  }
}

// ---------- merged: o3c (blocks 0..63) + absmax (blocks 64..127) ----------
__global__ __launch_bounds__(256) void o3cab_k(const float* __restrict__ Opart,
    const float* __restrict__ MLpart, u16* __restrict__ O3Th, u16* __restrict__ O3Tl,
    const float* __restrict__ k2, float* __restrict__ mx)
{
  int t = threadIdx.x;
  if (blockIdx.x < 64){
    int z = blockIdx.x;
    float m[4], l[4];
    #pragma unroll
    for (int c=0;c<4;c++){
      m[c] = MLpart[((size_t)(c*64+z)*256 + t)*2 + 0];
      l[c] = MLpart[((size_t)(c*64+z)*256 + t)*2 + 1];
    }
    float M = fmaxf(fmaxf(m[0],m[1]), fmaxf(m[2],m[3]));
    float w[4]; float L = 0.f;
    #pragma unroll
    for (int c=0;c<4;c++){ w[c] = fexp(m[c]-M); L += l[c]*w[c]; }
    float inv = 1.0f/L;
    for (int d0=0; d0<16; ++d0){
      f32x4 o = (f32x4){0.f,0.f,0.f,0.f};
      #pragma unroll
      for (int c=0;c<4;c++){
        f32x4 x = *(const f32x4*)(Opart + ((size_t)(c*64+z)*256 + t)*64 + d0*4);
        #pragma unroll
        for (int e=0;e<4;e++) o[e] += w[c]*x[e];
      }
      #pragma unroll
      for (int e=0;e<4;e++){
        float val = o[e]*inv;
        int d = d0*4+e;
        u16 h = f2bf(val);
        O3Th[((size_t)z*64 + d)*256 + t] = h;
        O3Tl[((size_t)z*64 + d)*256 + t] = f2bf(val - bf2f(h));
      }
    }
  } else {
    int z = blockIdx.x - 64;
    const float* A = k2 + (size_t)z*65536;
    float rsum=0.f, csum=0.f;
    for (int j=0;j<256;j++){
      rsum += fabsf(A[t*256+j]);
      csum += fabsf(A[j*256+t]);
    }
    #pragma unroll
    for (int d=1; d<64; d<<=1){
      rsum = fmaxf(rsum, __shfl_xor(rsum, d));
      csum = fmaxf(csum, __shfl_xor(csum, d));
    }
    __shared__ float red[8];
    int wv=t>>6, ln=t&63;
    if (ln==0){ red[wv]=rsum; red[4+wv]=csum; }
    __syncthreads();
    if (t==0){
      float mr = fmaxf(fmaxf(red[0],red[1]),fmaxf(red[2],red[3]));
      float mc = fmaxf(fmaxf(red[4],red[5]),fmaxf(red[6],red[7]));
      atomicMax((int*)&mx[0], __float_as_int(mr));
      atomicMax((int*)&mx[1], __float_as_int(mc));
    }
  }
}

// ---------- small helpers ----------
__global__ void fill_k(float* __restrict__ p, int n, float v){
  for (int i = blockIdx.x*256 + threadIdx.x; i < n; i += gridDim.x*256) p[i] = v;
}
// merged setup+pool: prep (0..76) + wtr4 (77..1100) + wtrsplit2 (1101..1612) + pool (1613..2636)
__global__ __launch_bounds__(256) void setup_k(
    const float* __restrict__ mask, float* __restrict__ rs,
    const float* __restrict__ bq, const float* __restrict__ bk,
    const float* __restrict__ bv, float* __restrict__ bqkv, float* __restrict__ mx,
    const float* __restrict__ Wq, const float* __restrict__ Wk,
    const float* __restrict__ Wv, const float* __restrict__ Wff,
    u16* __restrict__ Tqkv, u16* __restrict__ Tff,
    u16* __restrict__ QH, u16* __restrict__ QL,
    u16* __restrict__ KH, u16* __restrict__ KL,
    const float* __restrict__ X,
    u16* __restrict__ Xlh, u16* __restrict__ Xll,
    float* __restrict__ ml, u16* __restrict__ Xb)
{
  __shared__ float t[64][65];
  int b = blockIdx.x;
  if (b < 77){
    if (b < 64){
      int i = b*256 + threadIdx.x;
      rs[i] = mask[i] * 0.3535533905932738f;
    } else if (b < 76){
      int j = (b-64)*256 + threadIdx.x;
      bqkv[j] = (j<1024) ? bq[j] : (j<2048) ? bk[j-1024] : bv[j-2048];
    } else {
      if (threadIdx.x < 2) mx[threadIdx.x] = 0.f;
    }
    return;
  }
  if (b >= 1613){
    int bl = b - 1613; int bb = bl>>8; int l = bl&255;
    const float* Xp = X + ((size_t)bb*4096 + (size_t)l*16)*1024;
    const float* mp = mask + (size_t)bb*4096 + (size_t)l*16;
    int tt = threadIdx.x;
    f32x4 acc = (f32x4){0.f,0.f,0.f,0.f};
    float msum = 0.f;
    #pragma unroll
    for (int j=0;j<16;j++){
      float mj = mp[j];
      msum += mj;
      f32x4 x = *(const f32x4*)(Xp + (size_t)j*1024 + tt*4);
      us4 xb;
      #pragma unroll
      for (int c=0;c<4;c++){ acc[c] += mj*x[c]; xb[c] = f2bf(x[c]); }
      *(us4*)(Xb + ((size_t)bl*16 + j)*1024 + tt*4) = xb;
    }
    const float c0 = 0.02209708691207961f;  // 1/(16*sqrt(sqrt(64)))
    us4 h, lo;
    #pragma unroll
    for (int c=0;c<4;c++){
      float v = acc[c]*c0;
      h[c] = f2bf(v);
      lo[c] = f2bf(v - bf2f(h[c]));
    }
    *(us4*)(Xlh + (size_t)bl*1024 + tt*4) = h;
    *(us4*)(Xll + (size_t)bl*1024 + tt*4) = lo;
    if (tt==0) ml[bl] = msum * c0;
    return;
  }
  int tt = threadIdx.x; int c = tt&63, r0 = tt>>6;
  if (b < 77+1024){
    int f = b - 77;
    int zi = f >> 8; int r2 = f & 255; int ti = r2 & 15; int tj = r2 >> 4;
    const float* W = (zi==0)?Wq:(zi==1)?Wk:(zi==2)?Wv:Wff;
    u16* T = (zi==3)? Tff : (Tqkv + (size_t)zi*1048576);
    #pragma unroll
    for (int rr=0; rr<16; rr++){
      int r = rr*4 + r0;
      t[r][c] = W[(size_t)(ti*64+r)*1024 + tj*64 + c];
    }
    __syncthreads();
    #pragma unroll
    for (int rr=0; rr<16; rr++){
      int r = rr*4 + r0;
      T[(size_t)(tj*64 + r)*1024 + ti*64 + c] = f2bf(t[c][r]);
    }
  } else {
    int f = b - 77 - 1024;
    int zi = f >> 8; int r2 = f & 255; int ti = r2 & 15; int tj = r2 >> 4;
    const float* W = zi ? Wk : Wq;
    u16* TH = zi ? KH : QH;
    u16* TL = zi ? KL : QL;
    #pragma unroll
    for (int rr=0; rr<16; rr++){
      int r = rr*4 + r0;
      t[r][c] = W[(size_t)(ti*64+r)*1024 + tj*64 + c];
    }
    __syncthreads();
    #pragma unroll
    for (int rr=0; rr<16; rr++){
      int r = rr*4 + r0;
      float v = t[c][r];
      u16 h = f2bf(v);
      TH[(size_t)(tj*64 + r)*1024 + ti*64 + c] = h;
      TL[(size_t)(tj*64 + r)*1024 + ti*64 + c] = f2bf(v - bf2f(h));
    }
  }
}
// K2f -> K2 row splits, V0 col splits (direct), V0 row splits (transposed)
__global__ __launch_bounds__(256) void v0prep_k(const float* __restrict__ K2f, const float* __restrict__ mx,
    u16* __restrict__ K2h, u16* __restrict__ K2l,
    u16* __restrict__ V0rh, u16* __restrict__ V0rl,
    u16* __restrict__ V0ch, u16* __restrict__ V0cl)
{
  int z = blockIdx.y; int bx = blockIdx.x;
  int ti = bx>>2, tj = bx&3;
  __shared__ float tile[64][65];
  const float* A = K2f + (size_t)z*65536;
  int t = threadIdx.x; int c = t&63, r0 = t>>6;
  float invden = 1.0f/(mx[0]*mx[1]);
  #pragma unroll
  for (int rr=0; rr<16; rr++){
    int r = rr*4 + r0;
    float v = A[(size_t)(ti*64 + r)*256 + tj*64 + c];
    tile[r][c] = v;
    size_t idx = (size_t)z*65536 + (size_t)(ti*64+r)*256 + tj*64 + c;
    u16 h = f2bf(v);
    K2h[idx] = h; K2l[idx] = f2bf(v - bf2f(h));
    float w = v*invden;
    h = f2bf(w);
    V0ch[idx] = h; V0cl[idx] = f2bf(w - bf2f(h));
  }
  __syncthreads();
  #pragma unroll
  for (int rr=0; rr<16; rr++){
    int r = rr*4 + r0;
    float w = tile[c][r]*invden;
    size_t idx = (size_t)z*65536 + (size_t)(tj*64+r)*256 + ti*64 + c;
    u16 h = f2bf(w);
    V0rh[idx] = h; V0rl[idx] = f2bf(w - bf2f(h));
  }
}

// fused attn = softmax(Qb @ Klb^T) @ tTb : all-bf16 operands, gld16 staging
// softmax uses local-max rescaling: one cross-wave LDS round instead of two.
__device__ __forceinline__ int swz64(int row,int k){
  return row*64 + (((((k>>3)&7) ^ (row&7)))<<3) + (k&7);
}
__device__ __forceinline__ int swz256(int row,int k){
  return row*256 + ((((k>>3) ^ (row&7)))<<3) + (k&7);
}
__global__ __launch_bounds__(256) void attn_k(const u16* __restrict__ Qb,
    const u16* __restrict__ Klb, const u16* __restrict__ tTb,
    u16* __restrict__ attn){
  __shared__ u16 lds[32768];
  const int z = blockIdx.y;
  const int rows0 = blockIdx.x * 64;
  const int tid = threadIdx.x;
  const int lane = tid & 63, wv = tid>>6;
  const int lrow = lane & 15, kgrp = lane>>4;
  const u16* Qz = Qb + ((size_t)z*4096 + rows0)*64;
  const u16* Klz = Klb + (size_t)z*16384;
  const u16* tTz = tTb + (size_t)z*16384;

  #pragma unroll
  for (int i=0;i<8;i++){
    int s = i*256 + tid;
    int row = s>>3, c = s&7;
    gld16(Klz + (size_t)row*64 + ((c^(row&7))<<3), lds + (s & ~63)*8);
  }
  #pragma unroll
  for (int i=0;i<2;i++){
    int s = i*256 + tid;
    int row = s>>3, c = s&7;
    gld16(Qz + (size_t)row*64 + ((c^(row&7))<<3), lds + 16384 + (s & ~63)*8);
  }
  __syncthreads();

  f32x4 acc[4][4];
  #pragma unroll
  for (int i=0;i<4;i++)
    #pragma unroll
    for (int j=0;j<4;j++) acc[i][j] = (f32x4){0.f,0.f,0.f,0.f};
  #pragma unroll
  for (int ks=0; ks<2; ++ks){
    int ko = ks*32 + kgrp*8;
    short8 a[4], b[4];
    #pragma unroll
    for (int i=0;i<4;i++) a[i] = *(const short8*)&lds[16384 + swz64(16*i+lrow, ko)];
    #pragma unroll
    for (int j=0;j<4;j++) b[j] = *(const short8*)&lds[swz64(wv*64 + j*16 + lrow, ko)];
    #pragma unroll
    for (int i=0;i<4;i++)
      #pragma unroll
      for (int j=0;j<4;j++) acc[i][j] = mfma16(a[i], b[j], acc[i][j]);
  }
  __syncthreads();   // Kl & Q dead

  #pragma unroll
  for (int i=0;i<8;i++){
    int s = i*256 + tid;
    int row = s>>5, c = s&31;
    int gch = (c & ~7) | ((c ^ row) & 7);
    gld16(tTz + (size_t)row*256 + (gch<<3), lds + 16384 + (s & ~63)*8);
  }

  // merged softmax: pre-barrier local max + exp + local sum; one LDS round
  float* r0 = (float*)lds;
  float* r1 = r0 + 256;
  float lm_ir[4][4];
  float inv_ir[4][4];
  #pragma unroll
  for (int i=0;i<4;i++)
    #pragma unroll
    for (int r=0;r<4;r++){
      float mx = fmaxf(fmaxf(acc[i][0][r], acc[i][1][r]), fmaxf(acc[i][2][r], acc[i][3][r]));
      #pragma unroll
      for (int d=1; d<16; d<<=1) mx = fmaxf(mx, __shfl_xor(mx, d));
      float s = 0.f;
      #pragma unroll
      for (int j=0;j<4;j++){
        acc[i][j][r] = fexp(acc[i][j][r] - mx);
        s += acc[i][j][r];
      }
      #pragma unroll
      for (int d=1; d<16; d<<=1) s += __shfl_xor(s, d);
      lm_ir[i][r] = mx;
      if (lrow==0){
        int row = 16*i + kgrp*4 + r;
        r0[row*4 + wv] = mx;
        r1[row*4 + wv] = s;
      }
    }
  __syncthreads();
  #pragma unroll
  for (int i=0;i<4;i++)
    #pragma unroll
    for (int r=0;r<4;r++){
      int row = 16*i + kgrp*4 + r;
      float m0 = r0[row*4+0], m1 = r0[row*4+1], m2 = r0[row*4+2], m3 = r0[row*4+3];
      float gm = fmaxf(fmaxf(m0,m1), fmaxf(m2,m3));
      float total = r1[row*4+0]*fexp(m0-gm) + r1[row*4+1]*fexp(m1-gm)
                  + r1[row*4+2]*fexp(m2-gm) + r1[row*4+3]*fexp(m3-gm);
      inv_ir[i][r] = fexp(lm_ir[i][r]-gm) / total;
    }
  __syncthreads();   // all r0/r1 reads done before P overwrites

  #pragma unroll
  for (int i=0;i<4;i++)
    #pragma unroll
    for (int j=0;j<4;j++)
      #pragma unroll
      for (int r=0;r<4;r++){
        int row = 16*i + kgrp*4 + r;
        int l = wv*64 + j*16 + lrow;
        lds[swz256(row, l)] = f2bf(acc[i][j][r]*inv_ir[i][r]);
      }
  __syncthreads();   // also drains tT gld16

  f32x4 o[4];
  #pragma unroll
  for (int j=0;j<4;j++) o[j] = (f32x4){0.f,0.f,0.f,0.f};
  #pragma unroll
  for (int ks=0; ks<8; ++ks){
    int ko = ks*32 + kgrp*8;
    short8 a = *(const short8*)&lds[swz256(16*wv + lrow, ko)];
    #pragma unroll
    for (int j=0;j<4;j++){
      short8 bb = *(const short8*)&lds[16384 + swz256(j*16 + lrow, ko)];
      o[j] = mfma16(a, bb, o[j]);
    }
  }
  __syncthreads();
  #pragma unroll
  for (int j=0;j<4;j++)
    #pragma unroll
    for (int r=0;r<4;r++){
      int m = 16*wv + kgrp*4 + r;
      lds[m*64 + j*16 + lrow] = f2bf(o[j][r]);
    }
  __syncthreads();
  int b = z>>4, h = z&15;
  #pragma unroll
  for (int c=0;c<2;c++){
    int idx = c*256 + tid;
    int row = idx >> 3;
    int seg = idx & 7;
    us8 v = *(const us8*)&lds[row*64 + seg*8];
    *(us8*)&attn[((size_t)b*4096 + rows0 + row)*1024 + (size_t)h*64 + seg*8] = v;
  }
}

extern "C" void kernel_launch(void* const* d_in, const int* in_sizes, int n_in,
                              void* d_out, int out_size, void* d_ws, size_t ws_size,
                              hipStream_t stream) {
  (void)in_sizes; (void)n_in;
  const float* X    = (const float*)d_in[0];
  const float* mask = (const float*)d_in[1];
  const float* Wq   = (const float*)d_in[2];
  const float* bq   = (const float*)d_in[3];
  const float* Wk   = (const float*)d_in[4];
  const float* bk   = (const float*)d_in[5];
  const float* Wv   = (const float*)d_in[6];
  const float* bv   = (const float*)d_in[7];
  const float* Wff  = (const float*)d_in[8];
  const float* bff  = (const float*)d_in[9];
  float* outp = (float*)d_out;
  char* ws = (char*)d_ws;

  auto MiB = [](size_t x){ return x<<20; };
  // ---- static layout ----
  const size_t O_QB   = 0;
  const size_t O_KB   = MiB(32);
  const size_t O_VB   = MiB(64);
  const size_t O_XB   = MiB(96);
  const size_t O_RG[4][2] = {
    {MiB(32),MiB(40)}, {MiB(48),MiB(56)}, {MiB(64),MiB(72)}, {MiB(80),MiB(88)} };
  const size_t O_QLH  = MiB(96),  O_QLL = MiB(98), O_KLL = MiB(100);
  const size_t O_OPART= MiB(96);
  const size_t O_MLP  = MiB(112);
  const size_t O_XAH  = MiB(96),  O_XAL = MiB(104);
  const size_t O_K2H  = MiB(112), O_K2L = MiB(120);
  const size_t O_K2F  = MiB(128);
  const size_t O_WQKVT= MiB(128);
  const size_t O_XLH  = MiB(134), O_XLL = MiB(136);
  const size_t O_WQTH = MiB(138), O_WQTL = MiB(140);
  const size_t O_QL   = MiB(144);
  const size_t O_TTB  = MiB(144);
  const size_t O_KL   = MiB(148);
  const size_t O_O3TH = MiB(152), O_O3TL = MiB(154);
  const size_t O_WKTH = MiB(152), O_WKTL = MiB(154);
  const size_t O_WFFT = MiB(156);
  const size_t O_KLB  = MiB(158);
  const size_t O_ATTN = MiB(32);
  const size_t O_RS   = MiB(162);
  const size_t O_ML   = O_RS + 65536;
  const size_t O_MX   = O_ML + 4096;
  const size_t O_BQKV = O_MX + 256;
  const size_t NEED   = O_BQKV + 16384;

  if (ws_size < NEED){
    fill_k<<<2048,256,0,stream>>>(outp, out_size, 1.0e9f);
    return;
  }

  u16*   Qb   = (u16*)(ws + O_QB);
  u16*   Kb   = (u16*)(ws + O_KB);
  u16*   Vb   = (u16*)(ws + O_VB);
  u16*   Xb   = (u16*)(ws + O_XB);
  u16*   WqkvT= (u16*)(ws + O_WQKVT);
  u16*   WffT = (u16*)(ws + O_WFFT);
  float* bqkv = (float*)(ws + O_BQKV);
  float* Ql   = (float*)(ws + O_QL);
  float* Kl   = (float*)(ws + O_KL);
  u16*   QlH  = (u16*)(ws + O_QLH);
  u16*   QlL  = (u16*)(ws + O_QLL);
  u16*   KlL  = (u16*)(ws + O_KLL);
  u16*   Klb  = (u16*)(ws + O_KLB);
  u16*   tTb  = (u16*)(ws + O_TTB);
  float* K2f  = (float*)(ws + O_K2F);
  float* rs   = (float*)(ws + O_RS);
  float* ml   = (float*)(ws + O_ML);
  float* Mx   = (float*)(ws + O_MX);
  float* Opart= (float*)(ws + O_OPART);
  float* MLp  = (float*)(ws + O_MLP);
  u16*   O3Th = (u16*)(ws + O_O3TH);
  u16*   O3Tl = (u16*)(ws + O_O3TL);
  u16*   K2h  = (u16*)(ws + O_K2H);
  u16*   K2l  = (u16*)(ws + O_K2L);
  u16*   XAh  = (u16*)(ws + O_XAH);
  u16*   XAl  = (u16*)(ws + O_XAL);
  u16*   Xlh  = (u16*)(ws + O_XLH);
  u16*   Xll  = (u16*)(ws + O_XLL);
  u16*   WqTh = (u16*)(ws + O_WQTH);
  u16*   WqTl = (u16*)(ws + O_WQTL);
  u16*   WkTh = (u16*)(ws + O_WKTH);
  u16*   WkTl = (u16*)(ws + O_WKTL);
  u16*   AttnB= (u16*)(ws + O_ATTN);
  u16* RGH[4]; u16* RGL[4];
  for (int i=0;i<4;i++){ RGH[i] = (u16*)(ws + O_RG[i][0]); RGL[i] = (u16*)(ws + O_RG[i][1]); }

  // merged prep + weight transposes + pool
  setup_k<<<2637,256,0,stream>>>(mask, rs, bq, bk, bv, bqkv, Mx,
      Wq, Wk, Wv, Wff, WqkvT, WffT, WqTh, WqTl, WkTh, WkTl,
      X, Xlh, Xll, ml, Xb);

  // fused QKV projection (128x128 tile, 8-wave blocks)
  fgemm_k<1><<<dim3(24,128),512,0,stream>>>(Xb, WqkvT, nullptr, Qb, Kb, Vb,
      16384, 3072, 1024, 24, bqkv, rs);

  // landmarks (split): Ql/Kl = Xl@W + ml*b; also emit hi/lo split images
  sgemm_k<2><<<dim3(16,16,1),256,0,stream>>>(Xlh, Xll, WqTh, WqTl, 1024, 0, 0,
      QlH, QlL, nullptr, nullptr, Ql, 0, 0, 0.f, 0.f, 1.f, bq, ml);
  sgemm_k<2><<<dim3(16,16,1),256,0,stream>>>(Xlh, Xll, WkTh, WkTl, 1024, 0, 0,
      Klb, KlL, nullptr, nullptr, Kl, 0, 0, 0.f, 0.f, 1.f, bk, ml);

  // k2 = softmax(Ql@Kl^T) -> f32 (split-staged)
  k2s_k<<<dim3(4,64),256,0,stream>>>(QlH, QlL, Klb, KlL, K2f);

  // O3 partials (flash, KV split x4) + merged combine+absmax
  o3p_k<<<dim3(4,4,64),256,0,stream>>>(Ql, Kb, Vb, mask, Opart, MLp);
  o3cab_k<<<128,256,0,stream>>>(Opart, MLp, O3Th, O3Tl, K2f, Mx);

  // Newton-Schulz pseudo-inverse of k2 (pre-split operands, region rotation)
  v0prep_k<<<dim3(16,64),256,0,stream>>>(K2f, Mx, K2h, K2l, RGH[1], RGL[1], RGH[0], RGL[0]);
  int vc=0, vr=1, kv=2, x2=3;
  for (int it=0; it<6; ++it){
    sgemm_k<0><<<dim3(4,4,64),256,0,stream>>>(K2h, K2l, RGH[vc], RGL[vc], 256, 65536, 65536,
        RGH[kv], RGL[kv], XAh, XAl, nullptr, 0, 0, 7.f, -1.f, 1.f, nullptr, nullptr);
    sgemm_k<0><<<dim3(4,4,64),256,0,stream>>>(RGH[kv], RGL[kv], XAh, XAl, 256, 65536, 65536,
        nullptr, nullptr, RGH[x2], RGL[x2], nullptr, 0, 0, 15.f, -1.f, 1.f, nullptr, nullptr);
    sgemm_k<0><<<dim3(4,4,64),256,0,stream>>>(RGH[kv], RGL[kv], RGH[x2], RGL[x2], 256, 65536, 65536,
        nullptr, nullptr, XAh, XAl, nullptr, 0, 0, 13.f, -1.f, 1.f, nullptr, nullptr);
    sgemm_k<0><<<dim3(4,4,64),256,0,stream>>>(RGH[vr], RGL[vr], XAh, XAl, 256, 65536, 65536,
        RGH[kv], RGL[kv], RGH[x2], RGL[x2], nullptr, 0, 0, 0.f, 1.f, 0.25f, nullptr, nullptr);
    int nvc=x2, nvr=kv, nkv=vc, nx2=vr;
    vc=nvc; vr=nvr; kv=nkv; x2=nx2;
  }
  // t = Vfinal @ O3 -> tT bf16 [z][64][256] directly
  sgemm_k<1><<<dim3(4,1,64),256,0,stream>>>(RGH[vr], RGL[vr], O3Th, O3Tl, 256, 65536, 16384,
      nullptr,nullptr, tTb, nullptr, nullptr, 0, 0, 0.f, 0.f, 1.f, nullptr, nullptr);

  // attn = softmax(Qb@Klb^T)@tTb -> bf16 [b][s][h*64+d]
  attn_k<<<dim3(64,64),256,0,stream>>>(Qb, Klb, tTb, AttnB);

  // out = attn @ Wff + bff -> f32 (128x128 tile, 8-wave blocks)
  fgemm_k<0><<<dim3(8,128),512,0,stream>>>(AttnB, WffT, outp, nullptr, nullptr, nullptr,
      16384, 1024, 1024, 8, bff, nullptr);
}